// Round 1
// baseline (395.210 us; speedup 1.0000x reference)
//
#include <hip/hip_runtime.h>
#include <hip/hip_bf16.h>

typedef unsigned short u16;
typedef short bf16x8 __attribute__((ext_vector_type(8)));
typedef float f32x4 __attribute__((ext_vector_type(4)));

#define EQ_SCALE   0.04419417382415922f     /* 1/sqrt(512) */
#define CONV_SCALE 0.014731391274719738f    /* 1/sqrt(512*9) */

// workspace layout (bytes)
#define WS_S   0                                  // f32 [8][512]
#define WS_ESC (16*1024)                          // f32 [8][512]  = conv_scale*demod
#define WS_WSQ (32*1024)                          // f32 [512][512]
#define WS_WT  (32*1024 + 1024*1024)              // bf16 [9][512][512]  (khw, o, ci)
#define WS_XS  (WS_WT + 9*512*512*2)              // bf16 [8][64][64][512] (b, y, x, ci)

__device__ __forceinline__ void gld16(void* l, const void* g) {
  __builtin_amdgcn_global_load_lds((const __attribute__((address_space(1))) void*)g,
                                   (__attribute__((address_space(3))) void*)l,
                                   16, 0, 0);
}

// round-to-nearest-even f32 -> bf16 bits
__device__ __forceinline__ u16 f2b_rne(float f) {
  union { float f; unsigned int i; } c; c.f = f;
  unsigned int r = (c.i + 0x7FFFu + ((c.i >> 16) & 1u)) >> 16;
  return (u16)r;
}

// s[b][i] = eq_scale * sum_j style[b][j]*modw[i][j] + mod_bias[i]
__global__ void k_style(const float* __restrict__ style, const float* __restrict__ mw,
                        const float* __restrict__ mb, float* __restrict__ s) {
  int idx = blockIdx.x * 256 + threadIdx.x;      // 4096
  int b = idx >> 9, i = idx & 511;
  const float* sr = style + (b << 9);
  const float* wr = mw + (i << 9);
  float acc = 0.f;
  for (int j = 0; j < 512; ++j) acc += sr[j] * wr[j];
  s[idx] = acc * EQ_SCALE + mb[i];
}

// wsq[o][i] = sum_khw weight[o][i][khw]^2
__global__ void k_wsq(const float* __restrict__ w, float* __restrict__ wsq) {
  int idx = blockIdx.x * 256 + threadIdx.x;      // 262144
  const float* p = w + idx * 9;
  float a = 0.f;
  for (int t = 0; t < 9; ++t) { float v = p[t]; a += v * v; }
  wsq[idx] = a;
}

// esc[b][o] = conv_scale * rsqrt(conv_scale^2 * sum_i wsq[o][i]*s[b][i]^2 + 1e-8)
__global__ void k_esc(const float* __restrict__ wsq, const float* __restrict__ s,
                      float* __restrict__ esc) {
  int idx = blockIdx.x * 256 + threadIdx.x;      // 4096
  int b = idx >> 9, o = idx & 511;
  const float* wr = wsq + (o << 9);
  const float* sr = s + (b << 9);
  float a = 0.f;
  for (int i = 0; i < 512; ++i) { float sv = sr[i]; a += wr[i] * sv * sv; }
  esc[idx] = CONV_SCALE * rsqrtf(CONV_SCALE * CONV_SCALE * a + 1e-8f);
}

// Wt[khw][o][i] = bf16(weight[o][i][khw])   (f32 -> bf16 relayout)
__global__ void k_wt(const float* __restrict__ w, u16* __restrict__ wt) {
  int idx = blockIdx.x * 256 + threadIdx.x;      // 262144 = o*512 + i
  const float* p = w + idx * 9;
  for (int t = 0; t < 9; ++t) wt[t * 262144 + idx] = f2b_rne(p[t]);
}

// xs[b][y][x][i] = bf16( x[b][i][y][x] * s[b][i] )   (NCHW->NHWC transpose + scale)
__global__ void k_xs(const float* __restrict__ x, const float* __restrict__ s,
                     u16* __restrict__ xs) {
  __shared__ u16 tile[64 * 66];
  int by = blockIdx.x;                 // b*64 + y
  int i0 = blockIdx.y << 6;
  int b = by >> 6, y = by & 63;
  int t = threadIdx.x, w = t >> 6, lane = t & 63;
  for (int k = 0; k < 16; ++k) {
    int il = w + (k << 2);
    int i = i0 + il;
    float v = x[((((b << 9) + i) << 6) | y) << 6 | lane] * s[(b << 9) + i];
    tile[lane * 66 + il] = f2b_rne(v);
  }
  __syncthreads();
  for (int k = 0; k < 16; ++k) {
    int xc = w + (k << 2);
    xs[((((b << 6) | y) << 6 | xc) << 9) + i0 + lane] = tile[xc * 66 + lane];
  }
}

// Conv: implicit GEMM. Block tile 128(o) x 256(4 output rows x 64 cols).
// 8 waves (2 o-halves x 4 rows), wave tile 64x64.
// Pipelined: double-buffered A (per-tap weight slice) and B (xs tile);
// ONE __syncthreads per tap, staging issued post-barrier, overlapped with MFMA.
__global__ void __launch_bounds__(512, 2) k_conv(
    const u16* __restrict__ wt, const u16* __restrict__ xs,
    const float* __restrict__ esc, const float* __restrict__ noise,
    const float* __restrict__ nwp, const float* __restrict__ abias,
    float* __restrict__ out) {
  __shared__ __align__(16) u16 ldsA[2][128 * 64];   // 2 x 16 KB: [o_local][ci] xor-swizzled
  __shared__ __align__(16) u16 ldsB[2][384 * 64];   // 2 x 48 KB: [6 rows x 64 cols][ci]

  const int t = threadIdx.x;
  const int w = t >> 6, lane = t & 63;
  const int wm = w >> 2, wn = w & 3;            // 2(o) x 4(row) wave grid
  const int quad = lane >> 4, l15 = lane & 15;
  const int o0 = blockIdx.x << 7;
  const int nt = blockIdx.y;                    // 0..127
  const int b = nt >> 4, y0 = (nt & 15) << 2;   // 4 output rows per tile

  // B staging gather offsets (element units): 6 input rows (y0-1 .. y0+4)
  int bgOff[6];
#pragma unroll
  for (int j = 0; j < 6; ++j) {
    int c = j * 512 + t;
    int pos = c >> 3, swz = c & 7;
    int ci16 = swz ^ (pos & 7);
    int tr = pos >> 6, col = pos & 63;
    int yy = y0 - 1 + tr; yy = yy < 0 ? 0 : (yy > 63 ? 63 : yy);
    bgOff[j] = ((((b << 6) + yy) << 6) + col) * 512 + ci16 * 8;
  }
  // A staging gather offsets
  int agOff[2];
#pragma unroll
  for (int j = 0; j < 2; ++j) {
    int c = j * 512 + t;
    int ol = c >> 3, swz = c & 7;
    int ci16 = swz ^ (ol & 7);
    agOff[j] = (o0 + ol) * 512 + ci16 * 8;
  }

  f32x4 acc[16];
#pragma unroll
  for (int i = 0; i < 16; ++i) acc[i] = (f32x4)0.f;

  int aBase[4], aXor[4];
#pragma unroll
  for (int mf = 0; mf < 4; ++mf) {
    int ol = wm * 64 + mf * 16 + l15;
    aBase[mf] = ol * 8;
    aXor[mf] = ol & 7;
  }

  // prologue: stage B[cib=0] -> ldsB[0], A[tap 0] -> ldsA[0]
#pragma unroll
  for (int j = 0; j < 6; ++j)
    gld16(&ldsB[0][(j * 512 + w * 64) * 8], xs + bgOff[j]);
#pragma unroll
  for (int j = 0; j < 2; ++j)
    gld16(&ldsA[0][(j * 512 + w * 64) * 8], wt + agOff[j]);

#pragma unroll 1
  for (int cib = 0; cib < 8; ++cib) {
    const u16* bR = ldsB[cib & 1];
#pragma unroll
    for (int khw = 0; khw < 9; ++khw) {
      const int par = (cib + khw) & 1;
      // ONE barrier per tap: drains my in-flight stage loads (vmcnt0) and
      // guarantees all waves are done reading the buffers we stage into next.
      __syncthreads();

      // prefetch next tap's A slice into the other parity buffer
      if (cib < 7 || khw < 8) {
        const int nkhw = (khw == 8) ? 0 : khw + 1;
        const int ncib = (khw == 8) ? cib + 1 : cib;
        u16* aW = (u16*)ldsA[par ^ 1];
#pragma unroll
        for (int j = 0; j < 2; ++j)
          gld16(aW + (j * 512 + w * 64) * 8,
                wt + agOff[j] + nkhw * 262144 + ncib * 64);
      }
      // prefetch next cib's B tile (3 taps early -> latency fully hidden)
      if (khw == 6 && cib < 7) {
        u16* bW = (u16*)ldsB[(cib & 1) ^ 1];
#pragma unroll
        for (int j = 0; j < 6; ++j)
          gld16(bW + (j * 512 + w * 64) * 8, xs + bgOff[j] + (cib + 1) * 64);
      }

      const u16* aR = ldsA[par];
      const int kh = khw / 3, kw = khw % 3;
      const int row_in = y0 + wn + kh - 1;
      if (row_in >= 0 && row_in < 64) {      // wave-uniform; no barrier inside
        const int tr = wn + kh;
        int bBase[4], bXor[4];
        bool bz[4];
#pragma unroll
        for (int nf = 0; nf < 4; ++nf) {
          int colo = nf * 16 + l15;
          int ci = colo + kw - 1;
          bz[nf] = (ci < 0) | (ci > 63);
          ci &= 63;
          int pos = tr * 64 + ci;
          bBase[nf] = pos * 8;
          bXor[nf] = pos & 7;
        }
#pragma unroll
        for (int ks = 0; ks < 2; ++ks) {
          const int kci = ks * 4 + quad;
          bf16x8 af[4], bf[4];
#pragma unroll
          for (int mf = 0; mf < 4; ++mf)
            af[mf] = *(const bf16x8*)(aR + (aBase[mf] + (kci ^ aXor[mf])) * 8);
#pragma unroll
          for (int nf = 0; nf < 4; ++nf) {
            bf16x8 v = *(const bf16x8*)(bR + (bBase[nf] + (kci ^ bXor[nf])) * 8);
            bf16x8 z = {0, 0, 0, 0, 0, 0, 0, 0};
            bf[nf] = bz[nf] ? z : v;
          }
          __builtin_amdgcn_s_setprio(1);
#pragma unroll
          for (int mf = 0; mf < 4; ++mf)
#pragma unroll
            for (int nf = 0; nf < 4; ++nf)
              acc[mf * 4 + nf] = __builtin_amdgcn_mfma_f32_16x16x32_bf16(
                  af[mf], bf[nf], acc[mf * 4 + nf], 0, 0, 0);
          __builtin_amdgcn_s_setprio(0);
        }
      }
    }
  }

  // epilogue: scale + noise + bias + leaky_relu*sqrt(2), f32 store
  const float nwv = nwp[0];
  const int y = y0 + wn;
#pragma unroll
  for (int mf = 0; mf < 4; ++mf) {
#pragma unroll
    for (int r = 0; r < 4; ++r) {
      int o = o0 + wm * 64 + mf * 16 + quad * 4 + r;
      float es = esc[(b << 9) + o];
      float ab = abias[o];
      int rowbase = ((((b << 9) + o) << 6) | y) << 6;
#pragma unroll
      for (int nf = 0; nf < 4; ++nf) {
        int col = nf * 16 + l15;
        int idx = rowbase | col;
        float v = acc[mf * 4 + nf][r] * es + nwv * noise[idx] + ab;
        v = (v < 0.f ? 0.2f * v : v) * 1.4142135623730951f;
        out[idx] = v;
      }
    }
  }
}

extern "C" void kernel_launch(void* const* d_in, const int* in_sizes, int n_in,
                              void* d_out, int out_size, void* d_ws, size_t ws_size,
                              hipStream_t stream) {
  const float* x      = (const float*)d_in[0];
  const float* style  = (const float*)d_in[1];
  const float* noise  = (const float*)d_in[2];
  const float* weight = (const float*)d_in[3];
  const float* mw     = (const float*)d_in[4];
  const float* mb     = (const float*)d_in[5];
  const float* nw     = (const float*)d_in[6];
  const float* ab     = (const float*)d_in[7];
  float* out = (float*)d_out;

  char* ws = (char*)d_ws;
  float* s   = (float*)(ws + WS_S);
  float* esc = (float*)(ws + WS_ESC);
  float* wsq = (float*)(ws + WS_WSQ);
  u16* wt    = (u16*)(ws + WS_WT);
  u16* xs    = (u16*)(ws + WS_XS);

  k_style<<<16, 256, 0, stream>>>(style, mw, mb, s);
  k_wsq<<<1024, 256, 0, stream>>>(weight, wsq);
  k_esc<<<16, 256, 0, stream>>>(wsq, s, esc);
  k_wt<<<1024, 256, 0, stream>>>(weight, wt);
  k_xs<<<dim3(512, 8), 256, 0, stream>>>(x, s, xs);
  k_conv<<<dim3(4, 128), 512, 0, stream>>>(wt, xs, esc, noise, nw, ab, out);
}